// Round 1
// baseline (585.339 us; speedup 1.0000x reference)
//
#include <hip/hip_runtime.h>
#include <math.h>

// ---------------------------------------------------------------------------
// GaitGraph: standardize -> GCN(2->64)+ReLU -> GCN(64->64)+ReLU -> mean-pool
//            -> linear 64->3.
// N=50000 nodes, E=800000 edges, G=2048 graphs, H=64.
// Baseline: wave-per-edge scatter aggregation with float atomics.
// ---------------------------------------------------------------------------

#define H 64

__device__ __forceinline__ float nan0(float v) {
    return isfinite(v) ? v : 0.0f;
}

// Load index i from a buffer that is either int32 or int64 (flag is64).
__device__ __forceinline__ int ld_idx(const void* p, long long i, int is64) {
    if (is64) return (int)((const long long*)p)[i];
    return ((const int*)p)[i];
}

// Detect int64 vs int32 for edge_index and batch.
// int64 (values < 2^31, >=0): every odd int32 word is a zero high-word.
// int32: sampled odd positions are real values (src ids / sorted graph ids),
//        essentially never all zero.
__global__ void k_detect(const int* ei, int nEi, const int* batch, int nB,
                         int* flags) {
    __shared__ int nz_e, nz_b;
    if (threadIdx.x == 0) { nz_e = 0; nz_b = 0; }
    __syncthreads();
    int i = threadIdx.x;  // 0..255
    long long pe = 1 + 2 * ((long long)i * ((nEi - 2) / 2) / 256);
    if (pe < nEi && ei[pe] != 0) nz_e = 1;
    long long pb = 1 + 2 * ((long long)i * ((nB - 2) / 2) / 256);
    if (pb < nB && batch[pb] != 0) nz_b = 1;
    __syncthreads();
    if (threadIdx.x == 0) {
        flags[0] = (nz_e == 0);  // 1 -> edge_index is int64
        flags[1] = (nz_b == 0);  // 1 -> batch is int64
    }
}

// Column sums + sumsq of the 2 input features (with nan_to_num).
__global__ void k_stats(const float* __restrict__ x, int N,
                        float* __restrict__ stats) {
    float s0 = 0, s1 = 0, q0 = 0, q1 = 0;
    int tid = blockIdx.x * blockDim.x + threadIdx.x;
    int stride = gridDim.x * blockDim.x;
    for (int n = tid; n < N; n += stride) {
        float2 v = reinterpret_cast<const float2*>(x)[n];
        float a = nan0(v.x), b = nan0(v.y);
        s0 += a; s1 += b; q0 += a * a; q1 += b * b;
    }
    for (int m = 32; m >= 1; m >>= 1) {
        s0 += __shfl_down(s0, m);
        s1 += __shfl_down(s1, m);
        q0 += __shfl_down(q0, m);
        q1 += __shfl_down(q1, m);
    }
    __shared__ float red[4][4];
    int w = threadIdx.x >> 6, lane = threadIdx.x & 63;
    if (lane == 0) { red[w][0] = s0; red[w][1] = s1; red[w][2] = q0; red[w][3] = q1; }
    __syncthreads();
    if (threadIdx.x == 0) {
        int nw = blockDim.x >> 6;
        float t0 = 0, t1 = 0, t2 = 0, t3 = 0;
        for (int i = 0; i < nw; i++) {
            t0 += red[i][0]; t1 += red[i][1]; t2 += red[i][2]; t3 += red[i][3];
        }
        atomicAdd(&stats[0], t0);
        atomicAdd(&stats[1], t1);
        atomicAdd(&stats[2], t2);
        atomicAdd(&stats[3], t3);
    }
}

// stats[4..7] = mu0, mu1, 1/(std0+1e-6), 1/(std1+1e-6)   (ddof=1)
__global__ void k_finalize(float* stats, int N) {
    if (threadIdx.x == 0 && blockIdx.x == 0) {
        float mu0 = stats[0] / N, mu1 = stats[1] / N;
        float v0 = (stats[2] - stats[0] * stats[0] / N) / (N - 1);
        float v1 = (stats[3] - stats[1] * stats[1] / N) / (N - 1);
        v0 = fmaxf(v0, 0.0f); v1 = fmaxf(v1, 0.0f);
        stats[4] = mu0; stats[5] = mu1;
        stats[6] = 1.0f / (sqrtf(v0) + 1e-6f);
        stats[7] = 1.0f / (sqrtf(v1) + 1e-6f);
    }
}

// In-degree histogram over dst (self-loops added later as +1).
__global__ void k_deg(const void* ei, int E, int* __restrict__ deg,
                      const int* __restrict__ flags) {
    int e = blockIdx.x * blockDim.x + threadIdx.x;
    if (e >= E) return;
    int is64 = flags[0];
    int d = ld_idx(ei, (long long)E + e, is64);
    atomicAdd(&deg[d], 1);
}

// In-place: int count -> float rsqrt(count+1)
__global__ void k_dinv(float* degf, int N) {
    int v = blockIdx.x * blockDim.x + threadIdx.x;
    if (v >= N) return;
    int c = reinterpret_cast<int*>(degf)[v];
    degf[v] = rsqrtf((float)(c + 1));
}

// h = standardize(x) @ W1   (IN=2): wave per node, lane = output feature.
__global__ void k_gemm1(const float* __restrict__ x, const float* __restrict__ W1,
                        const float* __restrict__ stats, float* __restrict__ h,
                        int N) {
    int t = blockIdx.x * blockDim.x + threadIdx.x;
    int n = t >> 6, j = t & 63;
    if (n >= N) return;
    float2 v = reinterpret_cast<const float2*>(x)[n];
    float a = (nan0(v.x) - stats[4]) * stats[6];
    float b = (nan0(v.y) - stats[5]) * stats[7];
    h[t] = a * W1[j] + b * W1[H + j];
}

// Edge scatter: out[dst,:] += h[src,:] * dinv[src]*dinv[dst]. Wave per edge.
__global__ void k_agg(const void* ei, const float* __restrict__ dinv,
                      const float* __restrict__ h, float* __restrict__ out,
                      int E, const int* __restrict__ flags) {
    int t = blockIdx.x * blockDim.x + threadIdx.x;
    int e = t >> 6, j = t & 63;
    if (e >= E) return;
    int is64 = flags[0];
    int s = ld_idx(ei, e, is64);
    int d = ld_idx(ei, (long long)E + e, is64);
    float w = dinv[s] * dinv[d];
    atomicAdd(&out[d * H + j], h[s * H + j] * w);
}

// y = relu(y + h*dinv^2 (self-loop) + bias)
__global__ void k_brelu(float* __restrict__ y, const float* __restrict__ h,
                        const float* __restrict__ dinv,
                        const float* __restrict__ bias, int N) {
    int t = blockIdx.x * blockDim.x + threadIdx.x;
    int n = t >> 6, j = t & 63;
    if (n >= N) return;
    float di = dinv[n];
    float val = y[t] + h[t] * di * di + bias[j];
    y[t] = fmaxf(val, 0.0f);
}

// hout = yin @ W2 (64x64). Wave per row; W2 staged in LDS; row broadcast
// via __shfl.
__global__ __launch_bounds__(256) void k_gemm2(const float* __restrict__ yin,
                                               const float* __restrict__ W2,
                                               float* __restrict__ hout, int N) {
    __shared__ float Ws[H * H];
    for (int i = threadIdx.x; i < H * H; i += blockDim.x) Ws[i] = W2[i];
    __syncthreads();
    int wid = threadIdx.x >> 6, lane = threadIdx.x & 63;
    int n = blockIdx.x * 4 + wid;
    if (n >= N) return;
    float yv = yin[n * H + lane];
    float acc = 0.0f;
#pragma unroll
    for (int k = 0; k < H; k++) {
        float v = __shfl(yv, k);
        acc += v * Ws[k * H + lane];
    }
    hout[n * H + lane] = acc;
}

// Per-graph sum + count (batch sorted; atomics).
__global__ void k_pool(const float* __restrict__ y, const void* batch,
                       float* __restrict__ pool, float* __restrict__ cnt, int N,
                       const int* __restrict__ flags) {
    int t = blockIdx.x * blockDim.x + threadIdx.x;
    int n = t >> 6, j = t & 63;
    if (n >= N) return;
    int is64 = flags[1];
    int g = ld_idx(batch, n, is64);
    atomicAdd(&pool[g * H + j], y[t]);
    if (j == 0) atomicAdd(&cnt[g], 1.0f);
}

// out[g,:] = (pool[g,:]/max(cnt,1)) @ Wc + bc. Wave per graph.
__global__ void k_classify(const float* __restrict__ pool,
                           const float* __restrict__ cnt,
                           const float* __restrict__ Wc,
                           const float* __restrict__ bc,
                           float* __restrict__ out, int G) {
    int t = blockIdx.x * blockDim.x + threadIdx.x;
    int g = t >> 6, j = t & 63;
    if (g >= G) return;
    float c = cnt[g];
    float p = pool[g * H + j] / fmaxf(c, 1.0f);
#pragma unroll
    for (int cc = 0; cc < 3; cc++) {
        float v = p * Wc[j * 3 + cc];
        for (int m = 32; m >= 1; m >>= 1) v += __shfl_xor(v, m);
        if (j == 0) out[g * 3 + cc] = v + bc[cc];
    }
}

extern "C" void kernel_launch(void* const* d_in, const int* in_sizes, int n_in,
                              void* d_out, int out_size, void* d_ws,
                              size_t ws_size, hipStream_t stream) {
    const float* x  = (const float*)d_in[0];
    const float* W1 = (const float*)d_in[1];
    const float* b1 = (const float*)d_in[2];
    const float* W2 = (const float*)d_in[3];
    const float* b2 = (const float*)d_in[4];
    const float* Wc = (const float*)d_in[5];
    const float* bc = (const float*)d_in[6];
    const void*  ei = d_in[7];
    const void*  batch = d_in[8];

    int N = in_sizes[0] / 2;
    int E = in_sizes[7] / 2;
    int G = out_size / 3;

    float* ws    = (float*)d_ws;
    float* A     = ws;                       // [N,64]
    float* B     = A + (size_t)N * H;        // [N,64]
    float* dinv  = B + (size_t)N * H;        // [N] (int histogram, then float)
    float* stats = dinv + N;                 // [8]
    float* pool  = stats + 8;                // [G,64]
    float* cnt   = pool + (size_t)G * H;     // [G]
    int*   flags = (int*)(cnt + G);          // [2]

    float* out = (float*)d_out;

    int nblk_nh = (N * H + 255) / 256;   // wave-per-node kernels
    int nblk_eh = (int)(((long long)E * H + 255) / 256);  // wave-per-edge

    k_detect<<<1, 256, 0, stream>>>((const int*)ei, in_sizes[7],
                                    (const int*)batch, in_sizes[8], flags);
    hipMemsetAsync(stats, 0, 8 * sizeof(float), stream);
    hipMemsetAsync(dinv, 0, (size_t)N * sizeof(float), stream);

    k_stats<<<128, 256, 0, stream>>>(x, N, stats);
    k_finalize<<<1, 64, 0, stream>>>(stats, N);
    k_deg<<<(E + 255) / 256, 256, 0, stream>>>(ei, E, (int*)dinv, flags);
    k_dinv<<<(N + 255) / 256, 256, 0, stream>>>(dinv, N);

    // Layer 1
    k_gemm1<<<nblk_nh, 256, 0, stream>>>(x, W1, stats, A, N);
    hipMemsetAsync(B, 0, (size_t)N * H * sizeof(float), stream);
    k_agg<<<nblk_eh, 256, 0, stream>>>(ei, dinv, A, B, E, flags);
    k_brelu<<<nblk_nh, 256, 0, stream>>>(B, A, dinv, b1, N);

    // Layer 2
    k_gemm2<<<(N + 3) / 4, 256, 0, stream>>>(B, W2, A, N);
    hipMemsetAsync(B, 0, (size_t)N * H * sizeof(float), stream);
    k_agg<<<nblk_eh, 256, 0, stream>>>(ei, dinv, A, B, E, flags);
    k_brelu<<<nblk_nh, 256, 0, stream>>>(B, A, dinv, b2, N);

    // Pool + classify
    hipMemsetAsync(pool, 0, (size_t)(G * H + G) * sizeof(float), stream);
    k_pool<<<nblk_nh, 256, 0, stream>>>(B, batch, pool, cnt, N, flags);
    k_classify<<<(G * H + 255) / 256, 256, 0, stream>>>(pool, cnt, Wc, bc, out, G);
}

// Round 3
// 327.239 us; speedup vs baseline: 1.7887x; 1.7887x over previous
//
#include <hip/hip_runtime.h>
#include <math.h>

// ---------------------------------------------------------------------------
// GaitGraph: standardize -> GCN(2->64)+ReLU -> GCN(64->64)+ReLU -> mean-pool
//            -> linear 64->3.   N=50000, E=800000, G=2048, H=64.
// R1: replace atomic scatter aggregation (194us each, WRITE=200MB) with
//     dst-CSR build + pull-gather aggregation fused with selfloop+bias+relu.
// R2: identical resubmit (previous bench died to container failure).
// ---------------------------------------------------------------------------

#define H 64

__device__ __forceinline__ float nan0(float v) {
    return isfinite(v) ? v : 0.0f;
}

// Load index i from a buffer that is either int32 or int64 (flag is64).
__device__ __forceinline__ int ld_idx(const void* p, long long i, int is64) {
    if (is64) return (int)((const long long*)p)[i];
    return ((const int*)p)[i];
}

// Detect int64 vs int32 for edge_index and batch (odd int32 words all zero
// => int64 high words).
__global__ void k_detect(const int* ei, int nEi, const int* batch, int nB,
                         int* flags) {
    __shared__ int nz_e, nz_b;
    if (threadIdx.x == 0) { nz_e = 0; nz_b = 0; }
    __syncthreads();
    int i = threadIdx.x;  // 0..255
    long long pe = 1 + 2 * ((long long)i * ((nEi - 2) / 2) / 256);
    if (pe < nEi && ei[pe] != 0) nz_e = 1;
    long long pb = 1 + 2 * ((long long)i * ((nB - 2) / 2) / 256);
    if (pb < nB && batch[pb] != 0) nz_b = 1;
    __syncthreads();
    if (threadIdx.x == 0) {
        flags[0] = (nz_e == 0);
        flags[1] = (nz_b == 0);
    }
}

// Column sums + sumsq of the 2 input features (with nan_to_num).
__global__ void k_stats(const float* __restrict__ x, int N,
                        float* __restrict__ stats) {
    float s0 = 0, s1 = 0, q0 = 0, q1 = 0;
    int tid = blockIdx.x * blockDim.x + threadIdx.x;
    int stride = gridDim.x * blockDim.x;
    for (int n = tid; n < N; n += stride) {
        float2 v = reinterpret_cast<const float2*>(x)[n];
        float a = nan0(v.x), b = nan0(v.y);
        s0 += a; s1 += b; q0 += a * a; q1 += b * b;
    }
    for (int m = 32; m >= 1; m >>= 1) {
        s0 += __shfl_down(s0, m);
        s1 += __shfl_down(s1, m);
        q0 += __shfl_down(q0, m);
        q1 += __shfl_down(q1, m);
    }
    __shared__ float red[4][4];
    int w = threadIdx.x >> 6, lane = threadIdx.x & 63;
    if (lane == 0) { red[w][0] = s0; red[w][1] = s1; red[w][2] = q0; red[w][3] = q1; }
    __syncthreads();
    if (threadIdx.x == 0) {
        int nw = blockDim.x >> 6;
        float t0 = 0, t1 = 0, t2 = 0, t3 = 0;
        for (int i = 0; i < nw; i++) {
            t0 += red[i][0]; t1 += red[i][1]; t2 += red[i][2]; t3 += red[i][3];
        }
        atomicAdd(&stats[0], t0);
        atomicAdd(&stats[1], t1);
        atomicAdd(&stats[2], t2);
        atomicAdd(&stats[3], t3);
    }
}

// stats[4..7] = mu0, mu1, 1/(std0+1e-6), 1/(std1+1e-6)   (ddof=1)
__global__ void k_finalize(float* stats, int N) {
    if (threadIdx.x == 0 && blockIdx.x == 0) {
        float mu0 = stats[0] / N, mu1 = stats[1] / N;
        float v0 = (stats[2] - stats[0] * stats[0] / N) / (N - 1);
        float v1 = (stats[3] - stats[1] * stats[1] / N) / (N - 1);
        v0 = fmaxf(v0, 0.0f); v1 = fmaxf(v1, 0.0f);
        stats[4] = mu0; stats[5] = mu1;
        stats[6] = 1.0f / (sqrtf(v0) + 1e-6f);
        stats[7] = 1.0f / (sqrtf(v1) + 1e-6f);
    }
}

// In-degree histogram over dst (self-loops handled as +1 later).
__global__ void k_deg(const void* ei, int E, int* __restrict__ counts,
                      const int* __restrict__ flags) {
    int e = blockIdx.x * blockDim.x + threadIdx.x;
    if (e >= E) return;
    int is64 = flags[0];
    int d = ld_idx(ei, (long long)E + e, is64);
    atomicAdd(&counts[d], 1);
}

// dinv[v] = rsqrt(counts[v]+1)
__global__ void k_dinv(const int* __restrict__ counts, float* __restrict__ dinv,
                       int N) {
    int v = blockIdx.x * blockDim.x + threadIdx.x;
    if (v >= N) return;
    dinv[v] = rsqrtf((float)(counts[v] + 1));
}

// --- 3-kernel exclusive scan of counts[N] -> offsets[N+1] ------------------
__global__ void k_scan1(const int* __restrict__ counts, int* __restrict__ part,
                        int* __restrict__ bsum, int N) {
    __shared__ int tmp[256];
    int i = blockIdx.x * 256 + threadIdx.x;
    int v = (i < N) ? counts[i] : 0;
    tmp[threadIdx.x] = v;
    __syncthreads();
    for (int off = 1; off < 256; off <<= 1) {
        int t = (threadIdx.x >= off) ? tmp[threadIdx.x - off] : 0;
        __syncthreads();
        tmp[threadIdx.x] += t;
        __syncthreads();
    }
    if (i < N) part[i] = tmp[threadIdx.x] - v;  // exclusive within block
    if (threadIdx.x == 255) bsum[blockIdx.x] = tmp[255];
}

__global__ void k_scan2(int* __restrict__ bsum, int nb) {  // nb <= 256
    __shared__ int tmp[256];
    int v = (threadIdx.x < nb) ? bsum[threadIdx.x] : 0;
    tmp[threadIdx.x] = v;
    __syncthreads();
    for (int off = 1; off < 256; off <<= 1) {
        int t = (threadIdx.x >= off) ? tmp[threadIdx.x - off] : 0;
        __syncthreads();
        tmp[threadIdx.x] += t;
        __syncthreads();
    }
    if (threadIdx.x < nb) bsum[threadIdx.x] = tmp[threadIdx.x] - v;
}

__global__ void k_scan3(const int* __restrict__ part, const int* __restrict__ bsum,
                        int* __restrict__ offsets, int* __restrict__ cursor,
                        int N, int E) {
    int i = blockIdx.x * 256 + threadIdx.x;
    if (i < N) {
        int o = part[i] + bsum[blockIdx.x];
        offsets[i] = o;
        cursor[i] = o;
    }
    if (i == 0) offsets[N] = E;
}

// Scatter edges into CSR buckets: entry = (src, dinv[src]*dinv[dst]).
__global__ void k_scatter(const void* ei, const float* __restrict__ dinv,
                          int* __restrict__ cursor, int2* __restrict__ csr,
                          int E, const int* __restrict__ flags) {
    int e = blockIdx.x * blockDim.x + threadIdx.x;
    if (e >= E) return;
    int is64 = flags[0];
    int s = ld_idx(ei, e, is64);
    int d = ld_idx(ei, (long long)E + e, is64);
    float w = dinv[s] * dinv[d];
    int pos = atomicAdd(&cursor[d], 1);
    csr[pos] = make_int2(s, __float_as_int(w));
}

// h = standardize(x) @ W1   (IN=2): wave per node, lane = output feature.
__global__ void k_gemm1(const float* __restrict__ x, const float* __restrict__ W1,
                        const float* __restrict__ stats, float* __restrict__ h,
                        int N) {
    int t = blockIdx.x * blockDim.x + threadIdx.x;
    int n = t >> 6, j = t & 63;
    if (n >= N) return;
    float2 v = reinterpret_cast<const float2*>(x)[n];
    float a = (nan0(v.x) - stats[4]) * stats[6];
    float b = (nan0(v.y) - stats[5]) * stats[7];
    h[t] = a * W1[j] + b * W1[H + j];
}

// Pull-gather aggregation fused with selfloop + bias + relu.
// Wave per dst node; lane j = feature. Chunked broadcast of CSR entries.
__global__ __launch_bounds__(256) void k_gath(
    const int2* __restrict__ csr, const int* __restrict__ offsets,
    const float* __restrict__ h, const float* __restrict__ dinv,
    const float* __restrict__ bias, float* __restrict__ out, int N) {
    int t = blockIdx.x * blockDim.x + threadIdx.x;
    int n = t >> 6, j = t & 63;
    if (n >= N) return;
    int beg = offsets[n], end = offsets[n + 1];
    float di = dinv[n];
    float acc = h[(size_t)n * H + j] * di * di;  // self-loop
    for (int base = beg; base < end; base += 64) {
        int cnt = min(64, end - base);
        int2 entry;
        if (base + j < end) entry = csr[base + j];
        for (int k = 0; k < cnt; k++) {
            int s = __shfl(entry.x, k);
            float w = __int_as_float(__shfl(entry.y, k));
            acc += h[(size_t)s * H + j] * w;
        }
    }
    out[(size_t)n * H + j] = fmaxf(acc + bias[j], 0.0f);
}

// hout = yin @ W2 (64x64). Wave per row; W2 staged in LDS.
__global__ __launch_bounds__(256) void k_gemm2(const float* __restrict__ yin,
                                               const float* __restrict__ W2,
                                               float* __restrict__ hout, int N) {
    __shared__ float Ws[H * H];
    for (int i = threadIdx.x; i < H * H; i += blockDim.x) Ws[i] = W2[i];
    __syncthreads();
    int wid = threadIdx.x >> 6, lane = threadIdx.x & 63;
    int n = blockIdx.x * 4 + wid;
    if (n >= N) return;
    float yv = yin[n * H + lane];
    float acc = 0.0f;
#pragma unroll
    for (int k = 0; k < H; k++) {
        float v = __shfl(yv, k);
        acc += v * Ws[k * H + lane];
    }
    hout[n * H + lane] = acc;
}

// Per-graph sum + count (batch sorted; atomics).
__global__ void k_pool(const float* __restrict__ y, const void* batch,
                       float* __restrict__ pool, float* __restrict__ cnt, int N,
                       const int* __restrict__ flags) {
    int t = blockIdx.x * blockDim.x + threadIdx.x;
    int n = t >> 6, j = t & 63;
    if (n >= N) return;
    int is64 = flags[1];
    int g = ld_idx(batch, n, is64);
    atomicAdd(&pool[g * H + j], y[t]);
    if (j == 0) atomicAdd(&cnt[g], 1.0f);
}

// out[g,:] = (pool[g,:]/max(cnt,1)) @ Wc + bc. Wave per graph.
__global__ void k_classify(const float* __restrict__ pool,
                           const float* __restrict__ cnt,
                           const float* __restrict__ Wc,
                           const float* __restrict__ bc,
                           float* __restrict__ out, int G) {
    int t = blockIdx.x * blockDim.x + threadIdx.x;
    int g = t >> 6, j = t & 63;
    if (g >= G) return;
    float c = cnt[g];
    float p = pool[g * H + j] / fmaxf(c, 1.0f);
#pragma unroll
    for (int cc = 0; cc < 3; cc++) {
        float v = p * Wc[j * 3 + cc];
        for (int m = 32; m >= 1; m >>= 1) v += __shfl_xor(v, m);
        if (j == 0) out[g * 3 + cc] = v + bc[cc];
    }
}

extern "C" void kernel_launch(void* const* d_in, const int* in_sizes, int n_in,
                              void* d_out, int out_size, void* d_ws,
                              size_t ws_size, hipStream_t stream) {
    const float* x  = (const float*)d_in[0];
    const float* W1 = (const float*)d_in[1];
    const float* b1 = (const float*)d_in[2];
    const float* W2 = (const float*)d_in[3];
    const float* b2 = (const float*)d_in[4];
    const float* Wc = (const float*)d_in[5];
    const float* bc = (const float*)d_in[6];
    const void*  ei = d_in[7];
    const void*  batch = d_in[8];

    int N = in_sizes[0] / 2;
    int E = in_sizes[7] / 2;
    int G = out_size / 3;

    // Workspace layout (csr first for 8B alignment).
    int2*  csr     = (int2*)d_ws;                  // [E]
    float* A       = (float*)(csr + E);            // [N,64]
    float* B       = A + (size_t)N * H;            // [N,64]
    float* dinv    = B + (size_t)N * H;            // [N]
    float* stats   = dinv + N;                     // [8]
    float* pool    = stats + 8;                    // [G,64]
    float* cnt     = pool + (size_t)G * H;         // [G]
    int*   flags   = (int*)(cnt + G);              // [2]
    int*   counts  = flags + 2;                    // [N]
    int*   part    = counts + N;                   // [N]
    int*   bsum    = part + N;                     // [256]
    int*   offsets = bsum + 256;                   // [N+1]
    int*   cursor  = offsets + N + 1;              // [N]

    float* out = (float*)d_out;

    int nblk_nh = (N * H + 255) / 256;            // wave-per-node kernels
    int nblk_n256 = (N + 255) / 256;
    int nblk_e = (E + 255) / 256;

    k_detect<<<1, 256, 0, stream>>>((const int*)ei, in_sizes[7],
                                    (const int*)batch, in_sizes[8], flags);
    hipMemsetAsync(stats, 0, 8 * sizeof(float), stream);
    hipMemsetAsync(counts, 0, (size_t)N * sizeof(int), stream);
    hipMemsetAsync(pool, 0, (size_t)(G * H + G) * sizeof(float), stream);

    k_stats<<<128, 256, 0, stream>>>(x, N, stats);
    k_finalize<<<1, 64, 0, stream>>>(stats, N);

    // CSR build
    k_deg<<<nblk_e, 256, 0, stream>>>(ei, E, counts, flags);
    k_dinv<<<nblk_n256, 256, 0, stream>>>(counts, dinv, N);
    k_scan1<<<nblk_n256, 256, 0, stream>>>(counts, part, bsum, N);
    k_scan2<<<1, 256, 0, stream>>>(bsum, nblk_n256);
    k_scan3<<<nblk_n256, 256, 0, stream>>>(part, bsum, offsets, cursor, N, E);
    k_scatter<<<nblk_e, 256, 0, stream>>>(ei, dinv, cursor, csr, E, flags);

    // Layer 1
    k_gemm1<<<nblk_nh, 256, 0, stream>>>(x, W1, stats, A, N);
    k_gath<<<(N + 3) / 4, 256, 0, stream>>>(csr, offsets, A, dinv, b1, B, N);

    // Layer 2
    k_gemm2<<<(N + 3) / 4, 256, 0, stream>>>(B, W2, A, N);
    k_gath<<<(N + 3) / 4, 256, 0, stream>>>(csr, offsets, A, dinv, b2, B, N);

    // Pool + classify
    k_pool<<<nblk_nh, 256, 0, stream>>>(B, batch, pool, cnt, N, flags);
    k_classify<<<(G * H + 255) / 256, 256, 0, stream>>>(pool, cnt, Wc, bc, out, G);
}

// Round 5
// 236.752 us; speedup vs baseline: 2.4724x; 1.3822x over previous
//
#include <hip/hip_runtime.h>
#include <math.h>

// ---------------------------------------------------------------------------
// GaitGraph: standardize -> GCN(2->64)+ReLU -> GCN(64->64)+ReLU -> mean-pool
//            -> linear 64->3.   N=50000, E=800000, G=2048, H=64.
// R1: dst-CSR build + pull-gather (585 -> 327us).
// R4: (a) layer-1 rank-2 collapse: aggregate 2 scalars/edge, fuse expansion
//         into layer-2 GEMM staging (deletes gemm1 + 64-wide gath + B pass).
//     (b) k_gemm2 shfl-GEMM (61.6us, LDS-pipe-bound) -> 4x4 register-tile
//         f32 GEMM with float4 LDS reads.
//     (c) sorted-batch pooling via binary-searched ranges fused w/ classify.
// R5: identical resubmit (R4 bench died to container failure).
// ---------------------------------------------------------------------------

#define H 64

__device__ __forceinline__ float nan0(float v) {
    return isfinite(v) ? v : 0.0f;
}

// Load index i from a buffer that is either int32 or int64 (flag is64).
__device__ __forceinline__ int ld_idx(const void* p, long long i, int is64) {
    if (is64) return (int)((const long long*)p)[i];
    return ((const int*)p)[i];
}

// Detect int64 vs int32 for edge_index and batch (odd int32 words all zero
// => int64 high words).
__global__ void k_detect(const int* ei, int nEi, const int* batch, int nB,
                         int* flags) {
    __shared__ int nz_e, nz_b;
    if (threadIdx.x == 0) { nz_e = 0; nz_b = 0; }
    __syncthreads();
    int i = threadIdx.x;  // 0..255
    long long pe = 1 + 2 * ((long long)i * ((nEi - 2) / 2) / 256);
    if (pe < nEi && ei[pe] != 0) nz_e = 1;
    long long pb = 1 + 2 * ((long long)i * ((nB - 2) / 2) / 256);
    if (pb < nB && batch[pb] != 0) nz_b = 1;
    __syncthreads();
    if (threadIdx.x == 0) {
        flags[0] = (nz_e == 0);
        flags[1] = (nz_b == 0);
    }
}

// Column sums + sumsq of the 2 input features (with nan_to_num).
__global__ void k_stats(const float* __restrict__ x, int N,
                        float* __restrict__ stats) {
    float s0 = 0, s1 = 0, q0 = 0, q1 = 0;
    int tid = blockIdx.x * blockDim.x + threadIdx.x;
    int stride = gridDim.x * blockDim.x;
    for (int n = tid; n < N; n += stride) {
        float2 v = reinterpret_cast<const float2*>(x)[n];
        float a = nan0(v.x), b = nan0(v.y);
        s0 += a; s1 += b; q0 += a * a; q1 += b * b;
    }
    for (int m = 32; m >= 1; m >>= 1) {
        s0 += __shfl_down(s0, m);
        s1 += __shfl_down(s1, m);
        q0 += __shfl_down(q0, m);
        q1 += __shfl_down(q1, m);
    }
    __shared__ float red[4][4];
    int w = threadIdx.x >> 6, lane = threadIdx.x & 63;
    if (lane == 0) { red[w][0] = s0; red[w][1] = s1; red[w][2] = q0; red[w][3] = q1; }
    __syncthreads();
    if (threadIdx.x == 0) {
        int nw = blockDim.x >> 6;
        float t0 = 0, t1 = 0, t2 = 0, t3 = 0;
        for (int i = 0; i < nw; i++) {
            t0 += red[i][0]; t1 += red[i][1]; t2 += red[i][2]; t3 += red[i][3];
        }
        atomicAdd(&stats[0], t0);
        atomicAdd(&stats[1], t1);
        atomicAdd(&stats[2], t2);
        atomicAdd(&stats[3], t3);
    }
}

// stats[4..7] = mu0, mu1, 1/(std0+1e-6), 1/(std1+1e-6)   (ddof=1)
__global__ void k_finalize(float* stats, int N) {
    if (threadIdx.x == 0 && blockIdx.x == 0) {
        float mu0 = stats[0] / N, mu1 = stats[1] / N;
        float v0 = (stats[2] - stats[0] * stats[0] / N) / (N - 1);
        float v1 = (stats[3] - stats[1] * stats[1] / N) / (N - 1);
        v0 = fmaxf(v0, 0.0f); v1 = fmaxf(v1, 0.0f);
        stats[4] = mu0; stats[5] = mu1;
        stats[6] = 1.0f / (sqrtf(v0) + 1e-6f);
        stats[7] = 1.0f / (sqrtf(v1) + 1e-6f);
    }
}

// In-degree histogram over dst (self-loops handled as +1 later).
__global__ void k_deg(const void* ei, int E, int* __restrict__ counts,
                      const int* __restrict__ flags) {
    int e = blockIdx.x * blockDim.x + threadIdx.x;
    if (e >= E) return;
    int is64 = flags[0];
    int d = ld_idx(ei, (long long)E + e, is64);
    atomicAdd(&counts[d], 1);
}

// dinv[v] = rsqrt(counts[v]+1)
__global__ void k_dinv(const int* __restrict__ counts, float* __restrict__ dinv,
                       int N) {
    int v = blockIdx.x * blockDim.x + threadIdx.x;
    if (v >= N) return;
    dinv[v] = rsqrtf((float)(counts[v] + 1));
}

// --- 3-kernel exclusive scan of counts[N] -> offsets[N+1] ------------------
__global__ void k_scan1(const int* __restrict__ counts, int* __restrict__ part,
                        int* __restrict__ bsum, int N) {
    __shared__ int tmp[256];
    int i = blockIdx.x * 256 + threadIdx.x;
    int v = (i < N) ? counts[i] : 0;
    tmp[threadIdx.x] = v;
    __syncthreads();
    for (int off = 1; off < 256; off <<= 1) {
        int t = (threadIdx.x >= off) ? tmp[threadIdx.x - off] : 0;
        __syncthreads();
        tmp[threadIdx.x] += t;
        __syncthreads();
    }
    if (i < N) part[i] = tmp[threadIdx.x] - v;  // exclusive within block
    if (threadIdx.x == 255) bsum[blockIdx.x] = tmp[255];
}

__global__ void k_scan2(int* __restrict__ bsum, int nb) {  // nb <= 256
    __shared__ int tmp[256];
    int v = (threadIdx.x < nb) ? bsum[threadIdx.x] : 0;
    tmp[threadIdx.x] = v;
    __syncthreads();
    for (int off = 1; off < 256; off <<= 1) {
        int t = (threadIdx.x >= off) ? tmp[threadIdx.x - off] : 0;
        __syncthreads();
        tmp[threadIdx.x] += t;
        __syncthreads();
    }
    if (threadIdx.x < nb) bsum[threadIdx.x] = tmp[threadIdx.x] - v;
}

__global__ void k_scan3(const int* __restrict__ part, const int* __restrict__ bsum,
                        int* __restrict__ offsets, int* __restrict__ cursor,
                        int N, int E) {
    int i = blockIdx.x * 256 + threadIdx.x;
    if (i < N) {
        int o = part[i] + bsum[blockIdx.x];
        offsets[i] = o;
        cursor[i] = o;
    }
    if (i == 0) offsets[N] = E;
}

// Scatter edges into CSR buckets: entry = (src, dinv[src]*dinv[dst]).
__global__ void k_scatter(const void* ei, const float* __restrict__ dinv,
                          int* __restrict__ cursor, int2* __restrict__ csr,
                          int E, const int* __restrict__ flags) {
    int e = blockIdx.x * blockDim.x + threadIdx.x;
    if (e >= E) return;
    int is64 = flags[0];
    int s = ld_idx(ei, e, is64);
    int d = ld_idx(ei, (long long)E + e, is64);
    float w = dinv[s] * dinv[d];
    int pos = atomicAdd(&cursor[d], 1);
    csr[pos] = make_int2(s, __float_as_int(w));
}

// Layer-1 rank-2 aggregation: S[d] = (sum_e w*a_s + dinv^2*a_d,
//                                     sum_e w*b_s + dinv^2*b_d)
// where (a,b) = standardized features. Thread per dst node.
__global__ void k_agg2(const int2* __restrict__ csr,
                       const int* __restrict__ offsets,
                       const float* __restrict__ x,
                       const float* __restrict__ stats,
                       const float* __restrict__ dinv,
                       float2* __restrict__ S, int N) {
    int n = blockIdx.x * blockDim.x + threadIdx.x;
    if (n >= N) return;
    float mu0 = stats[4], mu1 = stats[5], r0 = stats[6], r1 = stats[7];
    float2 xn = reinterpret_cast<const float2*>(x)[n];
    float di = dinv[n];
    float s0 = di * di * (nan0(xn.x) - mu0) * r0;
    float s1 = di * di * (nan0(xn.y) - mu1) * r1;
    int beg = offsets[n], end = offsets[n + 1];
    for (int k = beg; k < end; k++) {
        int2 e = csr[k];
        float w = __int_as_float(e.y);
        float2 xs = reinterpret_cast<const float2*>(x)[e.x];
        s0 += w * (nan0(xs.x) - mu0) * r0;
        s1 += w * (nan0(xs.y) - mu1) * r1;
    }
    S[n] = make_float2(s0, s1);
}

// Fused: expand layer-1 output y1[r][k] = relu(S0[r]*W1[0][k]+S1[r]*W1[1][k]
// +b1[k]) directly TRANSPOSED into LDS, then h2 = y1 @ W2 via 4x4 register
// tile per thread. Block = 64 rows x 64 cols, 256 threads.
__global__ __launch_bounds__(256) void k_l2fused(
    const float2* __restrict__ S, const float* __restrict__ W1,
    const float* __restrict__ b1, const float* __restrict__ W2,
    float* __restrict__ h2, int N) {
    __shared__ float At[64][64];  // At[k][r] = y1[r][k]
    __shared__ float Ws[64][64];  // Ws[k][c]
    int tid = threadIdx.x;
    int rbase = blockIdx.x * 64;
    for (int i = tid; i < 64 * 64; i += 256) {
        Ws[i >> 6][i & 63] = W2[i];
    }
    for (int i = tid; i < 64 * 64; i += 256) {
        int k = i >> 6, r = i & 63;
        int rr = min(rbase + r, N - 1);
        float2 s = S[rr];
        At[k][r] = fmaxf(s.x * W1[k] + s.y * W1[H + k] + b1[k], 0.0f);
    }
    __syncthreads();
    int rg = (tid & 15) * 4;  // row group
    int cg = (tid >> 4) * 4;  // col group
    float acc[4][4] = {{0}};
#pragma unroll
    for (int k = 0; k < 64; k++) {
        float4 a = *reinterpret_cast<const float4*>(&At[k][rg]);
        float4 b = *reinterpret_cast<const float4*>(&Ws[k][cg]);
        acc[0][0] += a.x * b.x; acc[0][1] += a.x * b.y;
        acc[0][2] += a.x * b.z; acc[0][3] += a.x * b.w;
        acc[1][0] += a.y * b.x; acc[1][1] += a.y * b.y;
        acc[1][2] += a.y * b.z; acc[1][3] += a.y * b.w;
        acc[2][0] += a.z * b.x; acc[2][1] += a.z * b.y;
        acc[2][2] += a.z * b.z; acc[2][3] += a.z * b.w;
        acc[3][0] += a.w * b.x; acc[3][1] += a.w * b.y;
        acc[3][2] += a.w * b.z; acc[3][3] += a.w * b.w;
    }
#pragma unroll
    for (int i = 0; i < 4; i++) {
        int r = rbase + rg + i;
        if (r < N) {
            *reinterpret_cast<float4*>(&h2[(size_t)r * H + cg]) =
                make_float4(acc[i][0], acc[i][1], acc[i][2], acc[i][3]);
        }
    }
}

// Pull-gather aggregation fused with selfloop + bias + relu (layer 2).
// Wave per dst node; lane j = feature. Chunked broadcast of CSR entries.
__global__ __launch_bounds__(256) void k_gath(
    const int2* __restrict__ csr, const int* __restrict__ offsets,
    const float* __restrict__ h, const float* __restrict__ dinv,
    const float* __restrict__ bias, float* __restrict__ out, int N) {
    int t = blockIdx.x * blockDim.x + threadIdx.x;
    int n = t >> 6, j = t & 63;
    if (n >= N) return;
    int beg = offsets[n], end = offsets[n + 1];
    float di = dinv[n];
    float acc = h[(size_t)n * H + j] * di * di;  // self-loop
    for (int base = beg; base < end; base += 64) {
        int cnt = min(64, end - base);
        int2 entry;
        if (base + j < end) entry = csr[base + j];
        for (int k = 0; k < cnt; k++) {
            int s = __shfl(entry.x, k);
            float w = __int_as_float(__shfl(entry.y, k));
            acc += h[(size_t)s * H + j] * w;
        }
    }
    out[(size_t)n * H + j] = fmaxf(acc + bias[j], 0.0f);
}

// Binary-search graph start offsets in sorted batch: gstart[g] = first i
// with batch[i] >= g, for g in [0, G].
__global__ void k_gsearch(const void* batch, int N, int G,
                          int* __restrict__ gstart,
                          const int* __restrict__ flags) {
    int g = blockIdx.x * blockDim.x + threadIdx.x;
    if (g > G) return;
    int is64 = flags[1];
    int lo = 0, hi = N;
    while (lo < hi) {
        int mid = (lo + hi) >> 1;
        if (ld_idx(batch, mid, is64) < g) lo = mid + 1; else hi = mid;
    }
    gstart[g] = lo;
}

// Mean-pool per graph (sorted ranges, no atomics) fused with 64x3 classify.
// Wave per graph; lane j = feature.
__global__ __launch_bounds__(256) void k_poolcls(
    const float* __restrict__ B, const int* __restrict__ gstart,
    const float* __restrict__ Wc, const float* __restrict__ bc,
    float* __restrict__ out, int G) {
    int t = blockIdx.x * blockDim.x + threadIdx.x;
    int g = t >> 6, j = t & 63;
    if (g >= G) return;
    int beg = gstart[g], end = gstart[g + 1];
    float acc = 0.0f;
    for (int n = beg; n < end; n++) acc += B[(size_t)n * H + j];
    float p = acc / (float)max(end - beg, 1);
#pragma unroll
    for (int c = 0; c < 3; c++) {
        float v = p * Wc[j * 3 + c];
        for (int m = 32; m >= 1; m >>= 1) v += __shfl_xor(v, m);
        if (j == 0) out[g * 3 + c] = v + bc[c];
    }
}

extern "C" void kernel_launch(void* const* d_in, const int* in_sizes, int n_in,
                              void* d_out, int out_size, void* d_ws,
                              size_t ws_size, hipStream_t stream) {
    const float* x  = (const float*)d_in[0];
    const float* W1 = (const float*)d_in[1];
    const float* b1 = (const float*)d_in[2];
    const float* W2 = (const float*)d_in[3];
    const float* b2 = (const float*)d_in[4];
    const float* Wc = (const float*)d_in[5];
    const float* bc = (const float*)d_in[6];
    const void*  ei = d_in[7];
    const void*  batch = d_in[8];

    int N = in_sizes[0] / 2;
    int E = in_sizes[7] / 2;
    int G = out_size / 3;

    // Workspace layout (8B-aligned entries first).
    int2*   csr     = (int2*)d_ws;                 // [E]
    float2* S       = (float2*)(csr + E);          // [N]
    float*  A       = (float*)(S + N);             // [N,64] h2
    float*  B       = A + (size_t)N * H;           // [N,64] layer-2 out
    float*  dinv    = B + (size_t)N * H;           // [N]
    float*  stats   = dinv + N;                    // [8]
    int*    flags   = (int*)(stats + 8);           // [2]
    int*    counts  = flags + 2;                   // [N]
    int*    part    = counts + N;                  // [N]
    int*    bsum    = part + N;                    // [256]
    int*    offsets = bsum + 256;                  // [N+1]
    int*    cursor  = offsets + N + 1;             // [N]
    int*    gstart  = cursor + N;                  // [G+1]

    float* out = (float*)d_out;

    int nblk_n256 = (N + 255) / 256;
    int nblk_e = (E + 255) / 256;

    k_detect<<<1, 256, 0, stream>>>((const int*)ei, in_sizes[7],
                                    (const int*)batch, in_sizes[8], flags);
    hipMemsetAsync(stats, 0, 8 * sizeof(float), stream);
    hipMemsetAsync(counts, 0, (size_t)N * sizeof(int), stream);

    k_stats<<<128, 256, 0, stream>>>(x, N, stats);
    k_finalize<<<1, 64, 0, stream>>>(stats, N);

    // CSR build
    k_deg<<<nblk_e, 256, 0, stream>>>(ei, E, counts, flags);
    k_dinv<<<nblk_n256, 256, 0, stream>>>(counts, dinv, N);
    k_scan1<<<nblk_n256, 256, 0, stream>>>(counts, part, bsum, N);
    k_scan2<<<1, 256, 0, stream>>>(bsum, nblk_n256);
    k_scan3<<<nblk_n256, 256, 0, stream>>>(part, bsum, offsets, cursor, N, E);
    k_scatter<<<nblk_e, 256, 0, stream>>>(ei, dinv, cursor, csr, E, flags);

    // Layer 1 (rank-2 collapsed aggregation)
    k_agg2<<<nblk_n256, 256, 0, stream>>>(csr, offsets, x, stats, dinv, S, N);

    // Layer 2: fused expand+GEMM, then pull-gather
    k_l2fused<<<(N + 63) / 64, 256, 0, stream>>>(S, W1, b1, W2, A, N);
    k_gath<<<(N + 3) / 4, 256, 0, stream>>>(csr, offsets, A, dinv, b2, B, N);

    // Pool + classify (sorted batch, no atomics)
    k_gsearch<<<(G + 256) / 256, 256, 0, stream>>>(batch, N, G, gstart, flags);
    k_poolcls<<<(G * H + 255) / 256, 256, 0, stream>>>(B, gstart, Wc, bc, out, G);
}